// Round 7
// baseline (465.848 us; speedup 1.0000x reference)
//
#include <hip/hip_runtime.h>
#include <math.h>

typedef unsigned long long u64;

#define W 768
#define H 768
#define NP (768*768)
#define NB 8
#define WPR 12              // u64 words per row (768/64)
#define NW (NB*H*WPR)       // total words per bit buffer = 73728
#define TH 16               // output rows per block in tiled vertical convs
#define P12N 73728          // floats per p12 angle region (8*768*12)

#define PADI(q) ((q) + ((q) >> 5))   // LDS pad: +1 word per 32

// ---------- ws layout (bytes) ----------
// 1024    : wtab (floats, 1536 entries):
//           [0..106] gpadH, [128..290] gpadV
//           [384+p*64]  6 uniform-17 horizontal tables (41 real entries at [3..43], zero-padded):
//                p: 0=h0c 1=h0s 2=h1c 3=h2c 4=h2s 5=h3c
//           [768+q*128] 6 vertical tables (tap j at [31+j], zero-padded):
//                q: 0=v0c(R12) 1=v0s(R12) 2=v1c(R17) 3=v2c(R12) 4=v2s(R12) 5=v3c(R17)
// 16384   : sc (u32): [0..7] imgMinEnc [8..15] imgMaxEnc [16..23] predMinEnc
//           [24..31] predMaxEnc [32..63] fsum(f32) [64..127] changed(unused)
// 20480   : p12[4 angles][73728] f32
// 1310720 : maskBits u64[NW]
// 1900544 : seedBits u64[NW]
// 2490368 : reachBits u64[NW]
// 4 MiB   : planes: 0:b0(tmp) 1:b1(enh) 8:f0 9:f1 10:f2 11:f3 (2..7 unused)

__device__ __forceinline__ unsigned fenc(float f) {
    unsigned b = __float_as_uint(f);
    return b ^ ((unsigned)((int)b >> 31) | 0x80000000u);
}
__device__ __forceinline__ float fdec(unsigned u) {
    unsigned b = (u & 0x80000000u) ? (u ^ 0x80000000u) : ~u;
    return __uint_as_float(b);
}
__device__ __forceinline__ int refl101(int i, int n) {
    if (i < 0) i = -i;
    if (i >= n) i = 2*n - 2 - i;
    return i;
}
__device__ __forceinline__ int symref(int i, int n) {
    if (i < 0) i = -1 - i;
    if (i >= n) i = 2*n - 1 - i;
    return i;
}

// ---------------- init: weight tables + scalar init ----------------
__global__ void initK(float* wtab, unsigned* sc) {
    int t = threadIdx.x;
    double sig = 15.5, ssum = 0.0;
    for (int i = 0; i < 101; i++) { double xx = i - 50; ssum += exp(-xx*xx/(2.0*sig*sig)); }
    for (int i = t; i < 107; i += 256) {        // gpadH: tap j at [3+j]
        float v = 0.f; int j = i - 3;
        if (j >= 0 && j < 101) { double xx = j - 50; v = (float)(exp(-xx*xx/(2.0*sig*sig))/ssum); }
        wtab[i] = v;
    }
    for (int i = t; i < 163; i += 256) {        // gpadV: tap j at [31+j]
        float v = 0.f; int j = i - 31;
        if (j >= 0 && j < 101) { double xx = j - 50; v = (float)(exp(-xx*xx/(2.0*sig*sig))/ssum); }
        wtab[128 + i] = v;
    }
    const double thetas[4] = {45.0, 90.0, 135.0, 180.0};
    const int    rad[4]    = {12, 17, 12, 17};
    const double sg = ((1.0/M_PI) * sqrt(log(2.0)/2.0) * 3.0) / 0.1;
    const double C  = 1.0/(2.0*M_PI*sg*sg);
    const int hG[6]   = {0, 0, 1, 2, 2, 3};
    const int hSin[6] = {0, 1, 0, 0, 1, 0};
    for (int idx = t; idx < 6*64; idx += 256) {
        int p = idx / 64, i = idx % 64;
        int g = hG[p], r = rad[g];
        double th = thetas[g] * (M_PI / 180.0);
        double a  = 2.0*M_PI*0.1*cos(th);
        float v = 0.f;
        int d = i - 20;
        if (i < 41 && d >= -r && d <= r) {
            double dd = (double)d, G = exp(-0.5*dd*dd/(sg*sg));
            v = hSin[p] ? (float)(C*G*sin(a*dd)) : (float)(C*G*cos(a*dd));
        }
        wtab[384 + p*64 + i] = v;
    }
    const int vG[6]   = {0, 0, 1, 2, 2, 3};
    const int vSin[6] = {0, 1, 0, 0, 1, 0};
    for (int idx = t; idx < 6*128; idx += 256) {
        int q = idx / 128, i = idx % 128;
        int g = vG[q], r = rad[g];
        double th = thetas[g] * (M_PI / 180.0);
        double bb = 2.0*M_PI*0.1*sin(th);
        float v = 0.f;
        int j = i - 31;
        if (j >= 0 && j <= 2*r) {
            double dd = (double)(j - r), G = exp(-0.5*dd*dd/(sg*sg));
            v = vSin[q] ? (float)(G*sin(bb*dd)) : (float)(G*cos(bb*dd));
        }
        wtab[768 + q*128 + i] = v;
    }
    if (t < 8)  { sc[t] = 0xFFFFFFFFu; sc[8+t] = 0u; sc[16+t] = 0xFFFFFFFFu; sc[24+t] = 0u; }
    if (t >= 32 && t < 64) ((float*)sc)[t] = 0.f;        // fsum
    if (t >= 64 && t < 128) sc[t] = 0u;                  // unused
}

// ---------------- per-image min/max of img and pred ----------------
__global__ void reduceK(const float* __restrict__ img, const float* __restrict__ pred,
                        unsigned* sc) {
    int b = blockIdx.y;
    int base = b*NP + blockIdx.x*9216 + threadIdx.x;
    float imn = INFINITY, imx = -INFINITY, pmn = INFINITY, pmx = -INFINITY;
    for (int k = 0; k < 36; k++) {
        float v = img[base + k*256];  imn = fminf(imn, v); imx = fmaxf(imx, v);
        float p = pred[base + k*256]; pmn = fminf(pmn, p); pmx = fmaxf(pmx, p);
    }
    for (int off = 32; off; off >>= 1) {
        imn = fminf(imn, __shfl_down(imn, off));
        imx = fmaxf(imx, __shfl_down(imx, off));
        pmn = fminf(pmn, __shfl_down(pmn, off));
        pmx = fmaxf(pmx, __shfl_down(pmx, off));
    }
    __shared__ float s[4][4];
    int lane = threadIdx.x & 63, wv = threadIdx.x >> 6;
    if (lane == 0) { s[0][wv] = imn; s[1][wv] = imx; s[2][wv] = pmn; s[3][wv] = pmx; }
    __syncthreads();
    if (threadIdx.x == 0) {
        float a0 = s[0][0], a1 = s[1][0], a2 = s[2][0], a3 = s[3][0];
        for (int w = 1; w < 4; w++) {
            a0 = fminf(a0, s[0][w]); a1 = fmaxf(a1, s[1][w]);
            a2 = fminf(a2, s[2][w]); a3 = fmaxf(a3, s[3][w]);
        }
        atomicMin(&sc[b],      fenc(a0));
        atomicMax(&sc[8 + b],  fenc(a1));
        atomicMin(&sc[16 + b], fenc(a2));
        atomicMax(&sc[24 + b], fenc(a3));
    }
}

// ---------------- Gaussian blur H: 4 outputs/thread, padded LDS ----------------
__global__ __launch_bounds__(192) void gaussHK2(const float* __restrict__ img,
                                                float* __restrict__ out,
                                                const float* __restrict__ wt,
                                                const unsigned* __restrict__ sc) {
    int b = blockIdx.y, y = blockIdx.x, t = threadIdx.x;
    float mn = fdec(sc[b]), mx = fdec(sc[8 + b]);
    float den = mx - mn;
    __shared__ float sh[896];
    const float* row = img + ((size_t)b*H + y)*W;
    for (int q = t; q < 868; q += 192) {
        int gx = refl101(q - 50, W);
        sh[PADI(q)] = (row[gx] - mn) / den;
    }
    __syncthreads();
    float a0 = 0.f, a1 = 0.f, a2 = 0.f, a3 = 0.f;
    int qb = 4*t;
    #pragma unroll
    for (int p = 0; p < 104; p++) {
        float v = sh[PADI(qb + p)];
        a0 = __fmaf_rn(wt[p + 3], v, a0);
        a1 = __fmaf_rn(wt[p + 2], v, a1);
        a2 = __fmaf_rn(wt[p + 1], v, a2);
        a3 = __fmaf_rn(wt[p    ], v, a3);
    }
    float4 o; o.x = a0; o.y = a1; o.z = a2; o.w = a3;
    *(float4*)(out + ((size_t)b*H + y)*W + qb) = o;
}

// ---------------- Gaussian blur V: unroll x4, XCD-resident image ----------------
__global__ __launch_bounds__(128) void gaussVK4(const float* __restrict__ tmp,
                                                const float* __restrict__ img,
                                                float* __restrict__ enh,
                                                const float* __restrict__ wt,
                                                const unsigned* __restrict__ sc) {
    int bid = blockIdx.x;
    int b = bid & 7; int r_ = bid >> 3; int tile = r_ % 48; int strip = r_ / 48;
    int y0 = tile*TH, x = strip*128 + threadIdx.x;
    float acc[TH];
    #pragma unroll
    for (int k = 0; k < TH; k++) acc[k] = 0.f;
    const float* T = tmp + (size_t)b*NP;
    for (int base = 0; base < 116; base += 4) {
        int g0 = refl101(y0+base-50, H), g1 = refl101(y0+base-49, H),
            g2 = refl101(y0+base-48, H), g3 = refl101(y0+base-47, H);
        float v0 = T[g0*W+x], v1 = T[g1*W+x], v2 = T[g2*W+x], v3 = T[g3*W+x];
        #pragma unroll
        for (int k = 0; k < TH; k++) {
            float a = acc[k];
            a = __fmaf_rn(wt[base   -k+31], v0, a);
            a = __fmaf_rn(wt[base+1 -k+31], v1, a);
            a = __fmaf_rn(wt[base+2 -k+31], v2, a);
            a = __fmaf_rn(wt[base+3 -k+31], v3, a);
            acc[k] = a;
        }
    }
    float mn = fdec(sc[b]), mx = fdec(sc[8 + b]);
    float den = mx - mn;
    #pragma unroll
    for (int k = 0; k < TH; k++) {
        size_t o = ((size_t)b*H + y0 + k)*W + x;
        float vv = (img[o] - mn) / den;
        float e = vv - acc[k];
        e = fminf(fmaxf(e, 0.f), 1.f);
        enh[o] = e;
    }
}

// ------- fused Gabor H+V, one angle pair: R12 (cos+sin) -> fA, R17 (cos) -> fB -------
// H chain: table idx i=3..37 ascending, multiplicand enh[x-20+i] — identical pairing/order
// to the proven gaborHF chains (zero-padded edges value-preserving).
// V chain: identical index/order to the proven gaborV2 chains.
__global__ __launch_bounds__(128) void gaborHVK(
        const float* __restrict__ enh,
        float* __restrict__ fA, float* __restrict__ fB,
        const float* __restrict__ Hc, const float* __restrict__ Hs,
        const float* __restrict__ Hb,
        const float* __restrict__ TcA, const float* __restrict__ TsA,
        const float* __restrict__ TcB,
        float* __restrict__ pA, float* __restrict__ pB) {
    int bid = blockIdx.x;
    int b = bid & 7; int r_ = bid >> 3; int tile = r_ % 48; int strip = r_ / 48;
    int y0 = tile*TH;
    int xl = threadIdx.x;
    int x = strip*128 + xl;
    __shared__ float se[50][162];
    const float* E = enh + (size_t)b*NP;
    int x0s = strip*128;
    for (int idx = threadIdx.x; idx < 50*162; idx += 128) {
        int rr = idx / 162, cc = idx - rr*162;
        int gy = symref(y0 + rr - 17, H);
        int gx = symref(x0s + cc - 17, W);
        se[rr][cc] = E[gy*W + gx];
    }
    __syncthreads();
    float a0[TH], a1[TH];
    #pragma unroll
    for (int k = 0; k < TH; k++) { a0[k] = 0.f; a1[k] = 0.f; }
    for (int base = 0; base < 50; ++base) {
        float hc = 0.f, hs = 0.f, hb = 0.f;
        #pragma unroll
        for (int j = 0; j < 35; ++j) {
            float v = se[base][xl + j];
            hc = __fmaf_rn(Hc[j + 3], v, hc);
            hs = __fmaf_rn(Hs[j + 3], v, hs);
            hb = __fmaf_rn(Hb[j + 3], v, hb);
        }
        #pragma unroll
        for (int k = 0; k < TH; k++) {
            int i26 = base - k + 26, i31 = base - k + 31;
            float t = a0[k];
            t = __fmaf_rn( TcA[i26], hc, t);
            t = __fmaf_rn(-TsA[i26], hs, t);
            a0[k] = t;
            a1[k] = __fmaf_rn(TcB[i31], hb, a1[k]);
        }
    }
    int g64 = strip*2 + (threadIdx.x >> 6);
    bool l0 = (threadIdx.x & 63) == 0;
    #pragma unroll
    for (int k = 0; k < TH; k++) {
        size_t o = ((size_t)b*H + y0 + k)*W + x;
        size_t po = ((size_t)b*H + y0 + k)*12 + g64;
        fA[o] = a0[k];
        float s = a0[k];
        for (int off = 32; off; off >>= 1) s += __shfl_down(s, off);
        if (l0) pA[po] = s;
        fB[o] = a1[k];
        s = a1[k];
        for (int off = 32; off; off >>= 1) s += __shfl_down(s, off);
        if (l0) pB[po] = s;
    }
}

// ---------------- deterministic per-image sums, all 4 angles ----------------
__global__ void sumKAll(const float* __restrict__ p12, float* fsum) {
    int b = blockIdx.x, g = blockIdx.y, t = threadIdx.x;
    const float* P = p12 + (size_t)g*P12N;
    float s = 0.f;
    for (int k = 0; k < 9; k++) {
        int idx = t + k*256;                 // 0..2303 == row*3 + strip
        int row = idx / 3, strip = idx - row*3;
        const float* Q = P + ((size_t)b*H + row)*12 + strip*4;
        float p4 = ((Q[0] + Q[1]) + Q[2]) + Q[3];
        s += p4;
    }
    __shared__ float sm[256];
    sm[t] = s; __syncthreads();
    for (int off = 128; off; off >>= 1) {
        if (t < off) sm[t] += sm[t + off];
        __syncthreads();
    }
    if (t == 0) fsum[g*8 + b] = sm[0];
}

// ---------------- seeds: row-tiled, 4 planes sequential in LDS (XCD swizzle) ----------------
__global__ __launch_bounds__(256) void seedK4(const float* __restrict__ f0,
        const float* __restrict__ f1, const float* __restrict__ f2,
        const float* __restrict__ f3, const float* __restrict__ fsum,
        u64* __restrict__ seedB) {
    int bid = blockIdx.x;
    int b = bid & 7; int r_ = bid >> 3;          // 0..143
    int y0 = (r_ % 48)*16; int xb = r_ / 48;     // 0..2
    int x0 = xb*256, t = threadIdx.x;
    __shared__ float sh[18][258];
    const float* planes[4] = {f0, f1, f2, f3};
    unsigned condMask = 0;
    #pragma unroll
    for (int a = 0; a < 4; a++) {
        const float* F = planes[a] + (size_t)b*NP;
        __syncthreads();
        for (int idx = t; idx < 18*258; idx += 256) {
            int rr = idx / 258, q = idx - rr*258;
            int gy = y0 - 1 + rr; gy = gy < 0 ? 0 : (gy > H-1 ? H-1 : gy);
            int gx = x0 - 1 + q;  gx = gx < 0 ? 0 : (gx > W-1 ? W-1 : gx);
            sh[rr][q] = F[gy*W + gx];
        }
        __syncthreads();
        float mean = fsum[a*8 + b] / 589824.f;
        #pragma unroll
        for (int r = 0; r < 16; r++) {
            float c = sh[r+1][t+1];
            float mx = c;
            mx = fmaxf(mx, sh[r  ][t]); mx = fmaxf(mx, sh[r  ][t+1]); mx = fmaxf(mx, sh[r  ][t+2]);
            mx = fmaxf(mx, sh[r+1][t]); mx = fmaxf(mx, sh[r+1][t+1]); mx = fmaxf(mx, sh[r+1][t+2]);
            mx = fmaxf(mx, sh[r+2][t]); mx = fmaxf(mx, sh[r+2][t+1]); mx = fmaxf(mx, sh[r+2][t+2]);
            if ((c == mx) && (c > mean)) condMask |= (1u << r);
        }
    }
    int wv = t >> 6, lane = t & 63;
    #pragma unroll
    for (int r = 0; r < 16; r++) {
        u64 m = __ballot((condMask >> r) & 1u);
        if (lane == 0)
            seedB[((size_t)b*H + y0 + r)*WPR + xb*4 + wv] = m;
    }
}

// ---------------- Sobel grad mask (bitpacked, XCD swizzle) ----------------
__global__ void sobelK(const float* __restrict__ enh, u64* __restrict__ maskB) {
    int bid = blockIdx.x;
    int b = bid & 7; int r_ = bid >> 3;     // 0..2303
    int y = r_ / 3; int xs = r_ - 3*y;
    int x = xs*256 + threadIdx.x;
    const float* E = enh + (size_t)b*NP;
    int ym = y > 0 ? y-1 : 1, yp = y < H-1 ? y+1 : H-2;   // reflect101
    int xm = x > 0 ? x-1 : 1, xp = x < W-1 ? x+1 : W-2;
    float a00 = E[ym*W + xm], a01 = E[ym*W + x], a02 = E[ym*W + xp];
    float a10 = E[y*W + xm],                     a12 = E[y*W + xp];
    float a20 = E[yp*W + xm], a21 = E[yp*W + x], a22 = E[yp*W + xp];
    float gx = __fmaf_rn(-1.f, a00, 0.f);
    gx = __fmaf_rn( 1.f, a02, gx);
    gx = __fmaf_rn(-2.f, a10, gx);
    gx = __fmaf_rn( 2.f, a12, gx);
    gx = __fmaf_rn(-1.f, a20, gx);
    gx = __fmaf_rn( 1.f, a22, gx);
    float gy = __fmaf_rn(-1.f, a00, 0.f);
    gy = __fmaf_rn(-2.f, a01, gy);
    gy = __fmaf_rn(-1.f, a02, gy);
    gy = __fmaf_rn( 1.f, a20, gy);
    gy = __fmaf_rn( 2.f, a21, gy);
    gy = __fmaf_rn( 1.f, a22, gy);
    float s = __fadd_rn(__fmul_rn(gx, gx), __fmul_rn(gy, gy));
    float grad = (float)sqrt((double)s);
    const float THR = (float)(0.0789 + 1.0*0.0774);
    bool m = grad >= THR;
    u64 bits = __ballot(m);
    if ((threadIdx.x & 63) == 0) {
        int word = xs*4 + (threadIdx.x >> 6);
        maskB[((size_t)b*H + y)*WPR + word] = bits;
    }
}

// ------- flood to fixed point, single launch: 1 block/image, 12 waves = 12 stripes -------
__global__ __launch_bounds__(768) void floodOneK(const u64* __restrict__ Mb,
                                                 const u64* __restrict__ seedB,
                                                 u64* __restrict__ Rb) {
    int b = blockIdx.x;
    int wv = threadIdx.x >> 6;      // stripe 0..11
    int lane = threadIdx.x & 63;
    const u64* M = Mb + (size_t)b*H*WPR;
    const u64* S = seedB + (size_t)b*H*WPR;
    u64* R = Rb + (size_t)b*H*WPR;
    u64 m[12], r[12];
    #pragma unroll
    for (int j = 0; j < 12; j++) {
        int row = j*64 + lane;
        m[j] = M[row*WPR + wv];
        r[j] = m[j] & S[row*WPR + wv];
    }
    __shared__ u64 eL[12][12], eR[12][12];
    __shared__ int go;
    unsigned cLmask = 0, cRmask = 0;
    while (true) {
        // in-stripe converge (full 2D within 64x768 stripe)
        while (true) {
            bool any = false;
            #pragma unroll
            for (int j = 0; j < 12; j++) {
                u64 top = (j > 0)  ? __shfl(r[j-1], 63) : 0ULL;
                u64 bot = (j < 11) ? __shfl(r[j+1], 0)  : 0ULL;
                u64 up = __shfl_up(r[j], 1);   if (lane == 0)  up = top;
                u64 dn = __shfl_down(r[j], 1); if (lane == 63) dn = bot;
                u64 D = up | r[j] | dn;
                u64 nr = (D | (D << 1) | (D >> 1)
                          | (u64)((cLmask >> j) & 1u)
                          | ((u64)((cRmask >> j) & 1u) << 63)) & m[j];
                if (nr != r[j]) any = true;
                r[j] = nr;
            }
            if (!__any(any)) break;
        }
        if (threadIdx.x == 0) go = 0;
        #pragma unroll
        for (int j = 0; j < 12; j++) {
            u64 bl = __ballot((r[j] & 1ULL) != 0ULL);
            u64 br = __ballot(((r[j] >> 63) & 1ULL) != 0ULL);
            if (lane == 0) { eL[wv][j] = bl; eR[wv][j] = br; }
        }
        __syncthreads();                       // A: edges + go=0 visible
        unsigned nL = 0, nR = 0;
        if (wv > 0) {
            #pragma unroll
            for (int j = 0; j < 12; j++) {
                u64 c = eR[wv-1][j];
                u64 p = (j > 0)  ? eR[wv-1][j-1] : 0ULL;
                u64 n = (j < 11) ? eR[wv-1][j+1] : 0ULL;
                u64 d = c | (c << 1) | (c >> 1) | (p >> 63) | (n << 63);
                nL |= (unsigned)((d >> lane) & 1ULL) << j;
            }
        }
        if (wv < 11) {
            #pragma unroll
            for (int j = 0; j < 12; j++) {
                u64 c = eL[wv+1][j];
                u64 p = (j > 0)  ? eL[wv+1][j-1] : 0ULL;
                u64 n = (j < 11) ? eL[wv+1][j+1] : 0ULL;
                u64 d = c | (c << 1) | (c >> 1) | (p >> 63) | (n << 63);
                nR |= (unsigned)((d >> lane) & 1ULL) << j;
            }
        }
        bool gained = false;
        #pragma unroll
        for (int j = 0; j < 12; j++) {
            if (((nL >> j) & 1u) && (m[j] & 1ULL) && !(r[j] & 1ULL)) gained = true;
            if (((nR >> j) & 1u) && ((m[j] >> 63) & 1ULL) && !((r[j] >> 63) & 1ULL)) gained = true;
        }
        if (__any(gained)) { if (lane == 0) go = 1; }
        __syncthreads();                       // B: all go writes done
        bool cont = (go != 0);
        __syncthreads();                       // C: all reads done before next go=0
        if (!cont) break;
        cLmask = nL; cRmask = nR;
    }
    #pragma unroll
    for (int j = 0; j < 12; j++)
        R[(j*64 + lane)*WPR + wv] = r[j];
}

// ---------------- final: out = (sigmoid?(pred)>0.5) | reach ----------------
__global__ void finalK(const float* __restrict__ pred, const u64* __restrict__ reachB,
                       const unsigned* __restrict__ sc, float* __restrict__ out) {
    int b = blockIdx.z, y = blockIdx.y, x = blockIdx.x*256 + threadIdx.x;
    float pmn = fdec(sc[16 + b]), pmx = fdec(sc[24 + b]);
    bool needSig = (pmx > 1.0f) || (pmn < 0.0f);
    float p = pred[((size_t)b*H + y)*W + x];
    float pv;
    if (needSig) {
        float e = (float)exp(-(double)p);
        pv = 1.f / (1.f + e);
    } else {
        pv = p;
    }
    bool on = pv > 0.5f;
    u64 w = reachB[((size_t)b*H + y)*WPR + (x >> 6)];
    on = on || ((w >> (x & 63)) & 1ULL);
    out[((size_t)b*H + y)*W + x] = on ? 1.f : 0.f;
}

extern "C" void kernel_launch(void* const* d_in, const int* in_sizes, int n_in,
                              void* d_out, int out_size, void* d_ws, size_t ws_size,
                              hipStream_t stream) {
    const float* pred = (const float*)d_in[0];
    const float* img  = (const float*)d_in[1];
    float* out = (float*)d_out;
    char* ws = (char*)d_ws;

    float*    wtab   = (float*)(ws + 1024);
    unsigned* sc     = (unsigned*)(ws + 16384);
    float*    fsum   = ((float*)sc) + 32;
    float*    p12    = (float*)(ws + 20480);
    u64*      maskB  = (u64*)(ws + 1310720);
    u64*      seedB  = (u64*)(ws + 1900544);
    u64*      reachB = (u64*)(ws + 2490368);
    const size_t PL = (size_t)NB*NP;                      // floats per plane
    float* plane = (float*)(ws + 4194304);
    float* b0  = plane;          // gauss tmp
    float* b1  = plane + PL;     // enh
    float* f0  = plane + 8*PL; float* f1 = plane + 9*PL;
    float* f2  = plane + 10*PL; float* f3 = plane + 11*PL;

    const float* gpadH = wtab;
    const float* gpadV = wtab + 128;

    initK<<<1, 256, 0, stream>>>(wtab, sc);
    reduceK<<<dim3(64, 8), 256, 0, stream>>>(img, pred, sc);

    dim3 gRow(768, 8);            // one image row per block (gauss H)
    gaussHK2<<<gRow, 192, 0, stream>>>(img, b0, gpadH, sc);
    gaussVK4<<<2304, 128, 0, stream>>>(b0, img, b1, gpadV, sc);

    sobelK<<<18432, 256, 0, stream>>>(b1, maskB);

    // angles 0 (R12 cos+sin) + 1 (R17 cos)
    gaborHVK<<<2304, 128, 0, stream>>>(b1, f0, f1,
                                       wtab + 384, wtab + 448, wtab + 512,
                                       wtab + 768, wtab + 896, wtab + 1024,
                                       p12, p12 + P12N);
    // angles 2 (R12 cos+sin) + 3 (R17 cos)
    gaborHVK<<<2304, 128, 0, stream>>>(b1, f2, f3,
                                       wtab + 576, wtab + 640, wtab + 704,
                                       wtab + 1152, wtab + 1280, wtab + 1408,
                                       p12 + 2*P12N, p12 + 3*P12N);
    sumKAll<<<dim3(8, 4), 256, 0, stream>>>(p12, fsum);

    seedK4<<<1152, 256, 0, stream>>>(f0, f1, f2, f3, fsum, seedB);

    floodOneK<<<8, 768, 0, stream>>>(maskB, seedB, reachB);

    finalK<<<dim3(3, H, 8), 256, 0, stream>>>(pred, reachB, sc, out);
}

// Round 8
// 272.641 us; speedup vs baseline: 1.7086x; 1.7086x over previous
//
#include <hip/hip_runtime.h>
#include <math.h>

typedef unsigned long long u64;

#define W 768
#define H 768
#define NP (768*768)
#define NB 8
#define WPR 12              // u64 words per row (768/64)
#define NW (NB*H*WPR)       // total words per bit buffer = 73728
#define TH 16               // output rows per block in tiled vertical convs
#define P12N 73728          // floats per p12 angle region (8*768*12)

#define PADI(q) ((q) + ((q) >> 5))   // LDS pad: +1 word per 32

// ---------- ws layout (bytes) ----------
// 1024    : wtab (floats, 1536 entries):
//           [0..106] gpadH, [128..290] gpadV
//           [384+p*64]  6 uniform-17 horizontal tables (41 real entries at [3..43]):
//                p: 0=h0c 1=h0s 2=h1c 3=h2c 4=h2s 5=h3c   (3,4 unused now)
//           [768+q*128] 6 vertical tables (tap j at [31+j], zero-padded):
//                q: 0=v0c(R12) 1=v0s(R12) 2=v1c(R17) 3=v2c 4=v2s 5=v3c(R17)
// 16384   : sc (u32): [0..7] imgMinEnc [8..15] imgMaxEnc [16..23] predMinEnc
//           [24..31] predMaxEnc [32..63] fsum(f32)
// 20480   : p12[4 angles][73728] f32
// 1310720 : maskBits u64[NW]
// 1900544 : seedBits u64[NW]
// 2490368 : reachBits u64[NW]
// 4 MiB   : planes: 0:b0(tmp) 1:b1(enh) 2:h0c 3:h0s 4:h1c 5:h3c 8:f0 9:f1 10:f2 11:f3

__device__ __forceinline__ unsigned fenc(float f) {
    unsigned b = __float_as_uint(f);
    return b ^ ((unsigned)((int)b >> 31) | 0x80000000u);
}
__device__ __forceinline__ float fdec(unsigned u) {
    unsigned b = (u & 0x80000000u) ? (u ^ 0x80000000u) : ~u;
    return __uint_as_float(b);
}
__device__ __forceinline__ int refl101(int i, int n) {
    if (i < 0) i = -i;
    if (i >= n) i = 2*n - 2 - i;
    return i;
}
__device__ __forceinline__ int symref(int i, int n) {
    if (i < 0) i = -1 - i;
    if (i >= n) i = 2*n - 1 - i;
    return i;
}

// ---------------- init: weight tables + scalar init ----------------
__global__ void initK(float* wtab, unsigned* sc) {
    int t = threadIdx.x;
    double sig = 15.5, ssum = 0.0;
    for (int i = 0; i < 101; i++) { double xx = i - 50; ssum += exp(-xx*xx/(2.0*sig*sig)); }
    for (int i = t; i < 107; i += 256) {        // gpadH: tap j at [3+j]
        float v = 0.f; int j = i - 3;
        if (j >= 0 && j < 101) { double xx = j - 50; v = (float)(exp(-xx*xx/(2.0*sig*sig))/ssum); }
        wtab[i] = v;
    }
    for (int i = t; i < 163; i += 256) {        // gpadV: tap j at [31+j]
        float v = 0.f; int j = i - 31;
        if (j >= 0 && j < 101) { double xx = j - 50; v = (float)(exp(-xx*xx/(2.0*sig*sig))/ssum); }
        wtab[128 + i] = v;
    }
    const double thetas[4] = {45.0, 90.0, 135.0, 180.0};
    const int    rad[4]    = {12, 17, 12, 17};
    const double sg = ((1.0/M_PI) * sqrt(log(2.0)/2.0) * 3.0) / 0.1;
    const double C  = 1.0/(2.0*M_PI*sg*sg);
    const int hG[6]   = {0, 0, 1, 2, 2, 3};
    const int hSin[6] = {0, 1, 0, 0, 1, 0};
    for (int idx = t; idx < 6*64; idx += 256) {
        int p = idx / 64, i = idx % 64;
        int g = hG[p], r = rad[g];
        double th = thetas[g] * (M_PI / 180.0);
        double a  = 2.0*M_PI*0.1*cos(th);
        float v = 0.f;
        int d = i - 20;
        if (i < 41 && d >= -r && d <= r) {
            double dd = (double)d, G = exp(-0.5*dd*dd/(sg*sg));
            v = hSin[p] ? (float)(C*G*sin(a*dd)) : (float)(C*G*cos(a*dd));
        }
        wtab[384 + p*64 + i] = v;
    }
    const int vG[6]   = {0, 0, 1, 2, 2, 3};
    const int vSin[6] = {0, 1, 0, 0, 1, 0};
    for (int idx = t; idx < 6*128; idx += 256) {
        int q = idx / 128, i = idx % 128;
        int g = vG[q], r = rad[g];
        double th = thetas[g] * (M_PI / 180.0);
        double bb = 2.0*M_PI*0.1*sin(th);
        float v = 0.f;
        int j = i - 31;
        if (j >= 0 && j <= 2*r) {
            double dd = (double)(j - r), G = exp(-0.5*dd*dd/(sg*sg));
            v = vSin[q] ? (float)(G*sin(bb*dd)) : (float)(G*cos(bb*dd));
        }
        wtab[768 + q*128 + i] = v;
    }
    if (t < 8)  { sc[t] = 0xFFFFFFFFu; sc[8+t] = 0u; sc[16+t] = 0xFFFFFFFFu; sc[24+t] = 0u; }
    if (t >= 32 && t < 64) ((float*)sc)[t] = 0.f;        // fsum
}

// ---------------- per-image min/max of img and pred ----------------
__global__ void reduceK(const float* __restrict__ img, const float* __restrict__ pred,
                        unsigned* sc) {
    int b = blockIdx.y;
    int base = b*NP + blockIdx.x*9216 + threadIdx.x;
    float imn = INFINITY, imx = -INFINITY, pmn = INFINITY, pmx = -INFINITY;
    for (int k = 0; k < 36; k++) {
        float v = img[base + k*256];  imn = fminf(imn, v); imx = fmaxf(imx, v);
        float p = pred[base + k*256]; pmn = fminf(pmn, p); pmx = fmaxf(pmx, p);
    }
    for (int off = 32; off; off >>= 1) {
        imn = fminf(imn, __shfl_down(imn, off));
        imx = fmaxf(imx, __shfl_down(imx, off));
        pmn = fminf(pmn, __shfl_down(pmn, off));
        pmx = fmaxf(pmx, __shfl_down(pmx, off));
    }
    __shared__ float s[4][4];
    int lane = threadIdx.x & 63, wv = threadIdx.x >> 6;
    if (lane == 0) { s[0][wv] = imn; s[1][wv] = imx; s[2][wv] = pmn; s[3][wv] = pmx; }
    __syncthreads();
    if (threadIdx.x == 0) {
        float a0 = s[0][0], a1 = s[1][0], a2 = s[2][0], a3 = s[3][0];
        for (int w = 1; w < 4; w++) {
            a0 = fminf(a0, s[0][w]); a1 = fmaxf(a1, s[1][w]);
            a2 = fminf(a2, s[2][w]); a3 = fmaxf(a3, s[3][w]);
        }
        atomicMin(&sc[b],      fenc(a0));
        atomicMax(&sc[8 + b],  fenc(a1));
        atomicMin(&sc[16 + b], fenc(a2));
        atomicMax(&sc[24 + b], fenc(a3));
    }
}

// ---------------- Gaussian blur H: 4 outputs/thread, padded LDS ----------------
__global__ __launch_bounds__(192) void gaussHK2(const float* __restrict__ img,
                                                float* __restrict__ out,
                                                const float* __restrict__ wt,
                                                const unsigned* __restrict__ sc) {
    int b = blockIdx.y, y = blockIdx.x, t = threadIdx.x;
    float mn = fdec(sc[b]), mx = fdec(sc[8 + b]);
    float den = mx - mn;
    __shared__ float sh[896];
    const float* row = img + ((size_t)b*H + y)*W;
    for (int q = t; q < 868; q += 192) {
        int gx = refl101(q - 50, W);
        sh[PADI(q)] = (row[gx] - mn) / den;
    }
    __syncthreads();
    float a0 = 0.f, a1 = 0.f, a2 = 0.f, a3 = 0.f;
    int qb = 4*t;
    #pragma unroll
    for (int p = 0; p < 104; p++) {
        float v = sh[PADI(qb + p)];
        a0 = __fmaf_rn(wt[p + 3], v, a0);
        a1 = __fmaf_rn(wt[p + 2], v, a1);
        a2 = __fmaf_rn(wt[p + 1], v, a2);
        a3 = __fmaf_rn(wt[p    ], v, a3);
    }
    float4 o; o.x = a0; o.y = a1; o.z = a2; o.w = a3;
    *(float4*)(out + ((size_t)b*H + y)*W + qb) = o;
}

// ---------------- Gaussian blur V: unroll x4, XCD-resident image ----------------
__global__ __launch_bounds__(128) void gaussVK4(const float* __restrict__ tmp,
                                                const float* __restrict__ img,
                                                float* __restrict__ enh,
                                                const float* __restrict__ wt,
                                                const unsigned* __restrict__ sc) {
    int bid = blockIdx.x;
    int b = bid & 7; int r_ = bid >> 3; int tile = r_ % 48; int strip = r_ / 48;
    int y0 = tile*TH, x = strip*128 + threadIdx.x;
    float acc[TH];
    #pragma unroll
    for (int k = 0; k < TH; k++) acc[k] = 0.f;
    const float* T = tmp + (size_t)b*NP;
    for (int base = 0; base < 116; base += 4) {
        int g0 = refl101(y0+base-50, H), g1 = refl101(y0+base-49, H),
            g2 = refl101(y0+base-48, H), g3 = refl101(y0+base-47, H);
        float v0 = T[g0*W+x], v1 = T[g1*W+x], v2 = T[g2*W+x], v3 = T[g3*W+x];
        #pragma unroll
        for (int k = 0; k < TH; k++) {
            float a = acc[k];
            a = __fmaf_rn(wt[base   -k+31], v0, a);
            a = __fmaf_rn(wt[base+1 -k+31], v1, a);
            a = __fmaf_rn(wt[base+2 -k+31], v2, a);
            a = __fmaf_rn(wt[base+3 -k+31], v3, a);
            acc[k] = a;
        }
    }
    float mn = fdec(sc[b]), mx = fdec(sc[8 + b]);
    float den = mx - mn;
    #pragma unroll
    for (int k = 0; k < TH; k++) {
        size_t o = ((size_t)b*H + y0 + k)*W + x;
        float vv = (img[o] - mn) / den;
        float e = vv - acc[k];
        e = fminf(fmaxf(e, 0.f), 1.f);
        enh[o] = e;
    }
}

// ---------------- fused Gabor H: 4 planes (h2c==h0c, h2s==-h0s dropped) ----------------
__global__ __launch_bounds__(192) void gaborHF4(const float* __restrict__ enh,
        float* __restrict__ h0c, float* __restrict__ h0s,
        float* __restrict__ h1c, float* __restrict__ h3c,
        const float* __restrict__ wt) {
    int b = blockIdx.y, y = blockIdx.x, t = threadIdx.x;
    __shared__ float sh[832];
    const float* row = enh + ((size_t)b*H + y)*W;
    for (int q = t; q < 802; q += 192) {
        int gx = symref(q - 17, W);
        sh[PADI(q)] = row[gx];
    }
    __syncthreads();
    const float* T0c = wt + 384; const float* T0s = wt + 448;
    const float* T1c = wt + 512; const float* T3c = wt + 704;
    float a0c[4] = {0,0,0,0}, a0s[4] = {0,0,0,0};
    float a1c[4] = {0,0,0,0}, a3c[4] = {0,0,0,0};
    int qb = 4*t;
    #pragma unroll
    for (int p = 0; p < 38; p++) {
        float v = sh[PADI(qb + p)];
        #pragma unroll
        for (int sub = 0; sub < 4; sub++) {
            int idx = p + 3 - sub;
            a0c[sub] = __fmaf_rn(T0c[idx], v, a0c[sub]);
            a0s[sub] = __fmaf_rn(T0s[idx], v, a0s[sub]);
            a1c[sub] = __fmaf_rn(T1c[idx], v, a1c[sub]);
            a3c[sub] = __fmaf_rn(T3c[idx], v, a3c[sub]);
        }
    }
    size_t o = ((size_t)b*H + y)*W + qb;
    *(float4*)(h0c + o) = make_float4(a0c[0], a0c[1], a0c[2], a0c[3]);
    *(float4*)(h0s + o) = make_float4(a0s[0], a0s[1], a0s[2], a0s[3]);
    *(float4*)(h1c + o) = make_float4(a1c[0], a1c[1], a1c[2], a1c[3]);
    *(float4*)(h3c + o) = make_float4(a3c[0], a3c[1], a3c[2], a3c[3]);
}

// ------- Gabor V, 45/135 pair: A=Vc*hc, B=Vs*hs -> f0=A-B, f2=A+B -------
__global__ __launch_bounds__(128) void gaborVAB(
        const float* __restrict__ hc, const float* __restrict__ hs,
        float* __restrict__ f0, float* __restrict__ f2,
        const float* __restrict__ Tc, const float* __restrict__ Ts,
        float* __restrict__ p0, float* __restrict__ p2) {
    int bid = blockIdx.x;
    int b = bid & 7; int r_ = bid >> 3; int tile = r_ % 48; int strip = r_ / 48;
    int y0 = tile*TH, x = strip*128 + threadIdx.x;
    float A[TH], Bm[TH];
    #pragma unroll
    for (int k = 0; k < TH; k++) { A[k] = 0.f; Bm[k] = 0.f; }
    const size_t pb = (size_t)b*NP;
    for (int base = 0; base < 50; base += 2) {
        int gA = symref(y0 + base - 17, H), gB = symref(y0 + base - 16, H);
        size_t oA = pb + (size_t)gA*W + x, oB = pb + (size_t)gB*W + x;
        float vcA = hc[oA], vsA = hs[oA];
        float vcB = hc[oB], vsB = hs[oB];
        #pragma unroll
        for (int k = 0; k < TH; k++) {
            int i26 = base - k + 26;
            float t = A[k];
            t = __fmaf_rn(Tc[i26],   vcA, t);
            t = __fmaf_rn(Tc[i26+1], vcB, t);
            A[k] = t;
            t = Bm[k];
            t = __fmaf_rn(Ts[i26],   vsA, t);
            t = __fmaf_rn(Ts[i26+1], vsB, t);
            Bm[k] = t;
        }
    }
    int g64 = strip*2 + (threadIdx.x >> 6);
    bool l0 = (threadIdx.x & 63) == 0;
    #pragma unroll
    for (int k = 0; k < TH; k++) {
        size_t o = ((size_t)b*H + y0 + k)*W + x;
        size_t po = ((size_t)b*H + y0 + k)*12 + g64;
        float v0 = A[k] - Bm[k];
        float v2 = A[k] + Bm[k];
        f0[o] = v0;
        float s = v0;
        for (int off = 32; off; off >>= 1) s += __shfl_down(s, off);
        if (l0) p0[po] = s;
        f2[o] = v2;
        s = v2;
        for (int off = 32; off; off >>= 1) s += __shfl_down(s, off);
        if (l0) p2[po] = s;
    }
}

// ------- Gabor V, 90/180 pair: two independent 1-plane chains -------
__global__ __launch_bounds__(128) void gaborV13(
        const float* __restrict__ h1, const float* __restrict__ h3,
        float* __restrict__ f1, float* __restrict__ f3,
        const float* __restrict__ T1, const float* __restrict__ T3,
        float* __restrict__ p1, float* __restrict__ p3) {
    int bid = blockIdx.x;
    int b = bid & 7; int r_ = bid >> 3; int tile = r_ % 48; int strip = r_ / 48;
    int y0 = tile*TH, x = strip*128 + threadIdx.x;
    float a1[TH], a3[TH];
    #pragma unroll
    for (int k = 0; k < TH; k++) { a1[k] = 0.f; a3[k] = 0.f; }
    const size_t pb = (size_t)b*NP;
    for (int base = 0; base < 50; base += 2) {
        int gA = symref(y0 + base - 17, H), gB = symref(y0 + base - 16, H);
        size_t oA = pb + (size_t)gA*W + x, oB = pb + (size_t)gB*W + x;
        float v1A = h1[oA], v3A = h3[oA];
        float v1B = h1[oB], v3B = h3[oB];
        #pragma unroll
        for (int k = 0; k < TH; k++) {
            int i31 = base - k + 31;
            float t = a1[k];
            t = __fmaf_rn(T1[i31],   v1A, t);
            t = __fmaf_rn(T1[i31+1], v1B, t);
            a1[k] = t;
            t = a3[k];
            t = __fmaf_rn(T3[i31],   v3A, t);
            t = __fmaf_rn(T3[i31+1], v3B, t);
            a3[k] = t;
        }
    }
    int g64 = strip*2 + (threadIdx.x >> 6);
    bool l0 = (threadIdx.x & 63) == 0;
    #pragma unroll
    for (int k = 0; k < TH; k++) {
        size_t o = ((size_t)b*H + y0 + k)*W + x;
        size_t po = ((size_t)b*H + y0 + k)*12 + g64;
        f1[o] = a1[k];
        float s = a1[k];
        for (int off = 32; off; off >>= 1) s += __shfl_down(s, off);
        if (l0) p1[po] = s;
        f3[o] = a3[k];
        s = a3[k];
        for (int off = 32; off; off >>= 1) s += __shfl_down(s, off);
        if (l0) p3[po] = s;
    }
}

// ---------------- deterministic per-image sums, all 4 angles ----------------
__global__ void sumKAll(const float* __restrict__ p12, float* fsum) {
    int b = blockIdx.x, g = blockIdx.y, t = threadIdx.x;
    const float* P = p12 + (size_t)g*P12N;
    float s = 0.f;
    for (int k = 0; k < 9; k++) {
        int idx = t + k*256;                 // 0..2303 == row*3 + strip
        int row = idx / 3, strip = idx - row*3;
        const float* Q = P + ((size_t)b*H + row)*12 + strip*4;
        float p4 = ((Q[0] + Q[1]) + Q[2]) + Q[3];
        s += p4;
    }
    __shared__ float sm[256];
    sm[t] = s; __syncthreads();
    for (int off = 128; off; off >>= 1) {
        if (t < off) sm[t] += sm[t + off];
        __syncthreads();
    }
    if (t == 0) fsum[g*8 + b] = sm[0];
}

// ---------------- seeds: row-tiled, 4 planes sequential in LDS (XCD swizzle) ----------------
__global__ __launch_bounds__(256) void seedK4(const float* __restrict__ f0,
        const float* __restrict__ f1, const float* __restrict__ f2,
        const float* __restrict__ f3, const float* __restrict__ fsum,
        u64* __restrict__ seedB) {
    int bid = blockIdx.x;
    int b = bid & 7; int r_ = bid >> 3;          // 0..143
    int y0 = (r_ % 48)*16; int xb = r_ / 48;     // 0..2
    int x0 = xb*256, t = threadIdx.x;
    __shared__ float sh[18][258];
    const float* planes[4] = {f0, f1, f2, f3};
    unsigned condMask = 0;
    #pragma unroll
    for (int a = 0; a < 4; a++) {
        const float* F = planes[a] + (size_t)b*NP;
        __syncthreads();
        for (int idx = t; idx < 18*258; idx += 256) {
            int rr = idx / 258, q = idx - rr*258;
            int gy = y0 - 1 + rr; gy = gy < 0 ? 0 : (gy > H-1 ? H-1 : gy);
            int gx = x0 - 1 + q;  gx = gx < 0 ? 0 : (gx > W-1 ? W-1 : gx);
            sh[rr][q] = F[gy*W + gx];
        }
        __syncthreads();
        float mean = fsum[a*8 + b] / 589824.f;
        #pragma unroll
        for (int r = 0; r < 16; r++) {
            float c = sh[r+1][t+1];
            float mx = c;
            mx = fmaxf(mx, sh[r  ][t]); mx = fmaxf(mx, sh[r  ][t+1]); mx = fmaxf(mx, sh[r  ][t+2]);
            mx = fmaxf(mx, sh[r+1][t]); mx = fmaxf(mx, sh[r+1][t+1]); mx = fmaxf(mx, sh[r+1][t+2]);
            mx = fmaxf(mx, sh[r+2][t]); mx = fmaxf(mx, sh[r+2][t+1]); mx = fmaxf(mx, sh[r+2][t+2]);
            if ((c == mx) && (c > mean)) condMask |= (1u << r);
        }
    }
    int wv = t >> 6, lane = t & 63;
    #pragma unroll
    for (int r = 0; r < 16; r++) {
        u64 m = __ballot((condMask >> r) & 1u);
        if (lane == 0)
            seedB[((size_t)b*H + y0 + r)*WPR + xb*4 + wv] = m;
    }
}

// ---------------- Sobel grad mask (bitpacked, XCD swizzle) ----------------
__global__ void sobelK(const float* __restrict__ enh, u64* __restrict__ maskB) {
    int bid = blockIdx.x;
    int b = bid & 7; int r_ = bid >> 3;     // 0..2303
    int y = r_ / 3; int xs = r_ - 3*y;
    int x = xs*256 + threadIdx.x;
    const float* E = enh + (size_t)b*NP;
    int ym = y > 0 ? y-1 : 1, yp = y < H-1 ? y+1 : H-2;   // reflect101
    int xm = x > 0 ? x-1 : 1, xp = x < W-1 ? x+1 : W-2;
    float a00 = E[ym*W + xm], a01 = E[ym*W + x], a02 = E[ym*W + xp];
    float a10 = E[y*W + xm],                     a12 = E[y*W + xp];
    float a20 = E[yp*W + xm], a21 = E[yp*W + x], a22 = E[yp*W + xp];
    float gx = __fmaf_rn(-1.f, a00, 0.f);
    gx = __fmaf_rn( 1.f, a02, gx);
    gx = __fmaf_rn(-2.f, a10, gx);
    gx = __fmaf_rn( 2.f, a12, gx);
    gx = __fmaf_rn(-1.f, a20, gx);
    gx = __fmaf_rn( 1.f, a22, gx);
    float gy = __fmaf_rn(-1.f, a00, 0.f);
    gy = __fmaf_rn(-2.f, a01, gy);
    gy = __fmaf_rn(-1.f, a02, gy);
    gy = __fmaf_rn( 1.f, a20, gy);
    gy = __fmaf_rn( 2.f, a21, gy);
    gy = __fmaf_rn( 1.f, a22, gy);
    float s = __fadd_rn(__fmul_rn(gx, gx), __fmul_rn(gy, gy));
    float grad = (float)sqrt((double)s);
    const float THR = (float)(0.0789 + 1.0*0.0774);
    bool m = grad >= THR;
    u64 bits = __ballot(m);
    if ((threadIdx.x & 63) == 0) {
        int word = xs*4 + (threadIdx.x >> 6);
        maskB[((size_t)b*H + y)*WPR + word] = bits;
    }
}

// ------- flood to fixed point, single launch: 1 block/image, 12 waves = 12 stripes -------
__global__ __launch_bounds__(768) void floodOneK(const u64* __restrict__ Mb,
                                                 const u64* __restrict__ seedB,
                                                 u64* __restrict__ Rb) {
    int b = blockIdx.x;
    int wv = threadIdx.x >> 6;      // stripe 0..11
    int lane = threadIdx.x & 63;
    const u64* M = Mb + (size_t)b*H*WPR;
    const u64* S = seedB + (size_t)b*H*WPR;
    u64* R = Rb + (size_t)b*H*WPR;
    u64 m[12], r[12];
    #pragma unroll
    for (int j = 0; j < 12; j++) {
        int row = j*64 + lane;
        m[j] = M[row*WPR + wv];
        r[j] = m[j] & S[row*WPR + wv];
    }
    __shared__ u64 eL[12][12], eR[12][12];
    __shared__ int go;
    unsigned cLmask = 0, cRmask = 0;
    while (true) {
        while (true) {
            bool any = false;
            #pragma unroll
            for (int j = 0; j < 12; j++) {
                u64 top = (j > 0)  ? __shfl(r[j-1], 63) : 0ULL;
                u64 bot = (j < 11) ? __shfl(r[j+1], 0)  : 0ULL;
                u64 up = __shfl_up(r[j], 1);   if (lane == 0)  up = top;
                u64 dn = __shfl_down(r[j], 1); if (lane == 63) dn = bot;
                u64 D = up | r[j] | dn;
                u64 nr = (D | (D << 1) | (D >> 1)
                          | (u64)((cLmask >> j) & 1u)
                          | ((u64)((cRmask >> j) & 1u) << 63)) & m[j];
                if (nr != r[j]) any = true;
                r[j] = nr;
            }
            if (!__any(any)) break;
        }
        if (threadIdx.x == 0) go = 0;
        #pragma unroll
        for (int j = 0; j < 12; j++) {
            u64 bl = __ballot((r[j] & 1ULL) != 0ULL);
            u64 br = __ballot(((r[j] >> 63) & 1ULL) != 0ULL);
            if (lane == 0) { eL[wv][j] = bl; eR[wv][j] = br; }
        }
        __syncthreads();                       // A: edges + go=0 visible
        unsigned nL = 0, nR = 0;
        if (wv > 0) {
            #pragma unroll
            for (int j = 0; j < 12; j++) {
                u64 c = eR[wv-1][j];
                u64 p = (j > 0)  ? eR[wv-1][j-1] : 0ULL;
                u64 n = (j < 11) ? eR[wv-1][j+1] : 0ULL;
                u64 d = c | (c << 1) | (c >> 1) | (p >> 63) | (n << 63);
                nL |= (unsigned)((d >> lane) & 1ULL) << j;
            }
        }
        if (wv < 11) {
            #pragma unroll
            for (int j = 0; j < 12; j++) {
                u64 c = eL[wv+1][j];
                u64 p = (j > 0)  ? eL[wv+1][j-1] : 0ULL;
                u64 n = (j < 11) ? eL[wv+1][j+1] : 0ULL;
                u64 d = c | (c << 1) | (c >> 1) | (p >> 63) | (n << 63);
                nR |= (unsigned)((d >> lane) & 1ULL) << j;
            }
        }
        bool gained = false;
        #pragma unroll
        for (int j = 0; j < 12; j++) {
            if (((nL >> j) & 1u) && (m[j] & 1ULL) && !(r[j] & 1ULL)) gained = true;
            if (((nR >> j) & 1u) && ((m[j] >> 63) & 1ULL) && !((r[j] >> 63) & 1ULL)) gained = true;
        }
        if (__any(gained)) { if (lane == 0) go = 1; }
        __syncthreads();                       // B: all go writes done
        bool cont = (go != 0);
        __syncthreads();                       // C: all reads done before next go=0
        if (!cont) break;
        cLmask = nL; cRmask = nR;
    }
    #pragma unroll
    for (int j = 0; j < 12; j++)
        R[(j*64 + lane)*WPR + wv] = r[j];
}

// ---------------- final: out = (sigmoid?(pred)>0.5) | reach ----------------
__global__ void finalK(const float* __restrict__ pred, const u64* __restrict__ reachB,
                       const unsigned* __restrict__ sc, float* __restrict__ out) {
    int b = blockIdx.z, y = blockIdx.y, x = blockIdx.x*256 + threadIdx.x;
    float pmn = fdec(sc[16 + b]), pmx = fdec(sc[24 + b]);
    bool needSig = (pmx > 1.0f) || (pmn < 0.0f);
    float p = pred[((size_t)b*H + y)*W + x];
    float pv;
    if (needSig) {
        float e = (float)exp(-(double)p);
        pv = 1.f / (1.f + e);
    } else {
        pv = p;
    }
    bool on = pv > 0.5f;
    u64 w = reachB[((size_t)b*H + y)*WPR + (x >> 6)];
    on = on || ((w >> (x & 63)) & 1ULL);
    out[((size_t)b*H + y)*W + x] = on ? 1.f : 0.f;
}

extern "C" void kernel_launch(void* const* d_in, const int* in_sizes, int n_in,
                              void* d_out, int out_size, void* d_ws, size_t ws_size,
                              hipStream_t stream) {
    const float* pred = (const float*)d_in[0];
    const float* img  = (const float*)d_in[1];
    float* out = (float*)d_out;
    char* ws = (char*)d_ws;

    float*    wtab   = (float*)(ws + 1024);
    unsigned* sc     = (unsigned*)(ws + 16384);
    float*    fsum   = ((float*)sc) + 32;
    float*    p12    = (float*)(ws + 20480);
    u64*      maskB  = (u64*)(ws + 1310720);
    u64*      seedB  = (u64*)(ws + 1900544);
    u64*      reachB = (u64*)(ws + 2490368);
    const size_t PL = (size_t)NB*NP;                      // floats per plane
    float* plane = (float*)(ws + 4194304);
    float* b0  = plane;          // gauss tmp
    float* b1  = plane + PL;     // enh
    float* h0c = plane + 2*PL; float* h0s = plane + 3*PL;
    float* h1c = plane + 4*PL; float* h3c = plane + 5*PL;
    float* f0  = plane + 8*PL; float* f1 = plane + 9*PL;
    float* f2  = plane + 10*PL; float* f3 = plane + 11*PL;

    const float* gpadH = wtab;
    const float* gpadV = wtab + 128;

    initK<<<1, 256, 0, stream>>>(wtab, sc);
    reduceK<<<dim3(64, 8), 256, 0, stream>>>(img, pred, sc);

    dim3 gRow(768, 8);            // one image row per block
    gaussHK2<<<gRow, 192, 0, stream>>>(img, b0, gpadH, sc);
    gaussVK4<<<2304, 128, 0, stream>>>(b0, img, b1, gpadV, sc);

    sobelK<<<18432, 256, 0, stream>>>(b1, maskB);

    gaborHF4<<<gRow, 192, 0, stream>>>(b1, h0c, h0s, h1c, h3c, wtab);

    // 45/135 shared pair -> f0, f2
    gaborVAB<<<2304, 128, 0, stream>>>(h0c, h0s, f0, f2,
                                       wtab + 768, wtab + 896,
                                       p12, p12 + 2*P12N);
    // 90/180 pair -> f1, f3
    gaborV13<<<2304, 128, 0, stream>>>(h1c, h3c, f1, f3,
                                       wtab + 1024, wtab + 1408,
                                       p12 + P12N, p12 + 3*P12N);
    sumKAll<<<dim3(8, 4), 256, 0, stream>>>(p12, fsum);

    seedK4<<<1152, 256, 0, stream>>>(f0, f1, f2, f3, fsum, seedB);

    floodOneK<<<8, 768, 0, stream>>>(maskB, seedB, reachB);

    finalK<<<dim3(3, H, 8), 256, 0, stream>>>(pred, reachB, sc, out);
}

// Round 9
// 254.806 us; speedup vs baseline: 1.8282x; 1.0700x over previous
//
#include <hip/hip_runtime.h>
#include <math.h>

typedef unsigned long long u64;

#define W 768
#define H 768
#define NP (768*768)
#define NB 8
#define WPR 12              // u64 words per row (768/64)
#define NW (NB*H*WPR)       // total words per bit buffer = 73728
#define TH 16               // output rows per block in tiled vertical convs
#define P12N 73728          // floats per p12 angle region (8*768*12)
#define FLOOD_PASSES 6

#define PADI(q) ((q) + ((q) >> 5))   // LDS pad: +1 word per 32

// ---------- ws layout (bytes) ----------
// 1024    : wtab (floats, 1536 entries):
//           [0..106] gpadH, [128..290] gpadV
//           [384+p*64]  6 uniform-17 horizontal tables (41 real entries at [3..43]):
//                p: 0=h0c 1=h0s 2=h1c 3=h2c 4=h2s 5=h3c   (3,4 unused)
//           [768+q*128] 6 vertical tables (tap j at [31+j], zero-padded):
//                q: 0=v0c(R12) 1=v0s(R12) 2=v1c(R17) 3=v2c 4=v2s 5=v3c(R17)
// 16384   : sc (u32): [0..7] imgMinEnc [8..15] imgMaxEnc [16..23] predMinEnc
//           [24..31] predMaxEnc [32..63] fsum(f32) [64..127] chg flags
// 20480   : p12[4 angles][73728] f32
// 1310720 : maskBits u64[NW]
// 1900544 : seedBits u64[NW]
// 2490368 : reachBits u64[NW]
// 4 MiB   : planes: 0:b0(tmp) 1:b1(enh) 2:h0c 3:h0s 4:h1c 5:h3c 8:f0 9:f1 10:f2 11:f3

__device__ __forceinline__ unsigned fenc(float f) {
    unsigned b = __float_as_uint(f);
    return b ^ ((unsigned)((int)b >> 31) | 0x80000000u);
}
__device__ __forceinline__ float fdec(unsigned u) {
    unsigned b = (u & 0x80000000u) ? (u ^ 0x80000000u) : ~u;
    return __uint_as_float(b);
}
__device__ __forceinline__ int refl101(int i, int n) {
    if (i < 0) i = -i;
    if (i >= n) i = 2*n - 2 - i;
    return i;
}
__device__ __forceinline__ int symref(int i, int n) {
    if (i < 0) i = -1 - i;
    if (i >= n) i = 2*n - 1 - i;
    return i;
}

// ---------------- init: weight tables + scalar init ----------------
__global__ void initK(float* wtab, unsigned* sc) {
    int t = threadIdx.x;
    double sig = 15.5, ssum = 0.0;
    for (int i = 0; i < 101; i++) { double xx = i - 50; ssum += exp(-xx*xx/(2.0*sig*sig)); }
    for (int i = t; i < 107; i += 256) {        // gpadH: tap j at [3+j]
        float v = 0.f; int j = i - 3;
        if (j >= 0 && j < 101) { double xx = j - 50; v = (float)(exp(-xx*xx/(2.0*sig*sig))/ssum); }
        wtab[i] = v;
    }
    for (int i = t; i < 163; i += 256) {        // gpadV: tap j at [31+j]
        float v = 0.f; int j = i - 31;
        if (j >= 0 && j < 101) { double xx = j - 50; v = (float)(exp(-xx*xx/(2.0*sig*sig))/ssum); }
        wtab[128 + i] = v;
    }
    const double thetas[4] = {45.0, 90.0, 135.0, 180.0};
    const int    rad[4]    = {12, 17, 12, 17};
    const double sg = ((1.0/M_PI) * sqrt(log(2.0)/2.0) * 3.0) / 0.1;
    const double C  = 1.0/(2.0*M_PI*sg*sg);
    const int hG[6]   = {0, 0, 1, 2, 2, 3};
    const int hSin[6] = {0, 1, 0, 0, 1, 0};
    for (int idx = t; idx < 6*64; idx += 256) {
        int p = idx / 64, i = idx % 64;
        int g = hG[p], r = rad[g];
        double th = thetas[g] * (M_PI / 180.0);
        double a  = 2.0*M_PI*0.1*cos(th);
        float v = 0.f;
        int d = i - 20;
        if (i < 41 && d >= -r && d <= r) {
            double dd = (double)d, G = exp(-0.5*dd*dd/(sg*sg));
            v = hSin[p] ? (float)(C*G*sin(a*dd)) : (float)(C*G*cos(a*dd));
        }
        wtab[384 + p*64 + i] = v;
    }
    const int vG[6]   = {0, 0, 1, 2, 2, 3};
    const int vSin[6] = {0, 1, 0, 0, 1, 0};
    for (int idx = t; idx < 6*128; idx += 256) {
        int q = idx / 128, i = idx % 128;
        int g = vG[q], r = rad[g];
        double th = thetas[g] * (M_PI / 180.0);
        double bb = 2.0*M_PI*0.1*sin(th);
        float v = 0.f;
        int j = i - 31;
        if (j >= 0 && j <= 2*r) {
            double dd = (double)(j - r), G = exp(-0.5*dd*dd/(sg*sg));
            v = vSin[q] ? (float)(G*sin(bb*dd)) : (float)(G*cos(bb*dd));
        }
        wtab[768 + q*128 + i] = v;
    }
    if (t < 8)  { sc[t] = 0xFFFFFFFFu; sc[8+t] = 0u; sc[16+t] = 0xFFFFFFFFu; sc[24+t] = 0u; }
    if (t >= 32 && t < 64) ((float*)sc)[t] = 0.f;        // fsum
    if (t >= 64 && t < 128) sc[t] = 0u;                  // chg flags
}

// ---------------- per-image min/max of img and pred ----------------
__global__ void reduceK(const float* __restrict__ img, const float* __restrict__ pred,
                        unsigned* sc) {
    int b = blockIdx.y;
    int base = b*NP + blockIdx.x*9216 + threadIdx.x;
    float imn = INFINITY, imx = -INFINITY, pmn = INFINITY, pmx = -INFINITY;
    for (int k = 0; k < 36; k++) {
        float v = img[base + k*256];  imn = fminf(imn, v); imx = fmaxf(imx, v);
        float p = pred[base + k*256]; pmn = fminf(pmn, p); pmx = fmaxf(pmx, p);
    }
    for (int off = 32; off; off >>= 1) {
        imn = fminf(imn, __shfl_down(imn, off));
        imx = fmaxf(imx, __shfl_down(imx, off));
        pmn = fminf(pmn, __shfl_down(pmn, off));
        pmx = fmaxf(pmx, __shfl_down(pmx, off));
    }
    __shared__ float s[4][4];
    int lane = threadIdx.x & 63, wv = threadIdx.x >> 6;
    if (lane == 0) { s[0][wv] = imn; s[1][wv] = imx; s[2][wv] = pmn; s[3][wv] = pmx; }
    __syncthreads();
    if (threadIdx.x == 0) {
        float a0 = s[0][0], a1 = s[1][0], a2 = s[2][0], a3 = s[3][0];
        for (int w = 1; w < 4; w++) {
            a0 = fminf(a0, s[0][w]); a1 = fmaxf(a1, s[1][w]);
            a2 = fminf(a2, s[2][w]); a3 = fmaxf(a3, s[3][w]);
        }
        atomicMin(&sc[b],      fenc(a0));
        atomicMax(&sc[8 + b],  fenc(a1));
        atomicMin(&sc[16 + b], fenc(a2));
        atomicMax(&sc[24 + b], fenc(a3));
    }
}

// ---------------- Gaussian blur H: 4 outputs/thread, padded LDS ----------------
__global__ __launch_bounds__(192) void gaussHK2(const float* __restrict__ img,
                                                float* __restrict__ out,
                                                const float* __restrict__ wt,
                                                const unsigned* __restrict__ sc) {
    int b = blockIdx.y, y = blockIdx.x, t = threadIdx.x;
    float mn = fdec(sc[b]), mx = fdec(sc[8 + b]);
    float den = mx - mn;
    __shared__ float sh[896];
    const float* row = img + ((size_t)b*H + y)*W;
    for (int q = t; q < 868; q += 192) {
        int gx = refl101(q - 50, W);
        sh[PADI(q)] = (row[gx] - mn) / den;
    }
    __syncthreads();
    float a0 = 0.f, a1 = 0.f, a2 = 0.f, a3 = 0.f;
    int qb = 4*t;
    #pragma unroll
    for (int p = 0; p < 104; p++) {
        float v = sh[PADI(qb + p)];
        a0 = __fmaf_rn(wt[p + 3], v, a0);
        a1 = __fmaf_rn(wt[p + 2], v, a1);
        a2 = __fmaf_rn(wt[p + 1], v, a2);
        a3 = __fmaf_rn(wt[p    ], v, a3);
    }
    float4 o; o.x = a0; o.y = a1; o.z = a2; o.w = a3;
    *(float4*)(out + ((size_t)b*H + y)*W + qb) = o;
}

// ---------------- Gaussian blur V: unroll x4, XCD-resident image ----------------
__global__ __launch_bounds__(128) void gaussVK4(const float* __restrict__ tmp,
                                                const float* __restrict__ img,
                                                float* __restrict__ enh,
                                                const float* __restrict__ wt,
                                                const unsigned* __restrict__ sc) {
    int bid = blockIdx.x;
    int b = bid & 7; int r_ = bid >> 3; int tile = r_ % 48; int strip = r_ / 48;
    int y0 = tile*TH, x = strip*128 + threadIdx.x;
    float acc[TH];
    #pragma unroll
    for (int k = 0; k < TH; k++) acc[k] = 0.f;
    const float* T = tmp + (size_t)b*NP;
    for (int base = 0; base < 116; base += 4) {
        int g0 = refl101(y0+base-50, H), g1 = refl101(y0+base-49, H),
            g2 = refl101(y0+base-48, H), g3 = refl101(y0+base-47, H);
        float v0 = T[g0*W+x], v1 = T[g1*W+x], v2 = T[g2*W+x], v3 = T[g3*W+x];
        #pragma unroll
        for (int k = 0; k < TH; k++) {
            float a = acc[k];
            a = __fmaf_rn(wt[base   -k+31], v0, a);
            a = __fmaf_rn(wt[base+1 -k+31], v1, a);
            a = __fmaf_rn(wt[base+2 -k+31], v2, a);
            a = __fmaf_rn(wt[base+3 -k+31], v3, a);
            acc[k] = a;
        }
    }
    float mn = fdec(sc[b]), mx = fdec(sc[8 + b]);
    float den = mx - mn;
    #pragma unroll
    for (int k = 0; k < TH; k++) {
        size_t o = ((size_t)b*H + y0 + k)*W + x;
        float vv = (img[o] - mn) / den;
        float e = vv - acc[k];
        e = fminf(fmaxf(e, 0.f), 1.f);
        enh[o] = e;
    }
}

// ---------------- fused Gabor H: 4 planes (h2c==h0c, h2s==-h0s dropped) ----------------
__global__ __launch_bounds__(192) void gaborHF4(const float* __restrict__ enh,
        float* __restrict__ h0c, float* __restrict__ h0s,
        float* __restrict__ h1c, float* __restrict__ h3c,
        const float* __restrict__ wt) {
    int b = blockIdx.y, y = blockIdx.x, t = threadIdx.x;
    __shared__ float sh[832];
    const float* row = enh + ((size_t)b*H + y)*W;
    for (int q = t; q < 802; q += 192) {
        int gx = symref(q - 17, W);
        sh[PADI(q)] = row[gx];
    }
    __syncthreads();
    const float* T0c = wt + 384; const float* T0s = wt + 448;
    const float* T1c = wt + 512; const float* T3c = wt + 704;
    float a0c[4] = {0,0,0,0}, a0s[4] = {0,0,0,0};
    float a1c[4] = {0,0,0,0}, a3c[4] = {0,0,0,0};
    int qb = 4*t;
    #pragma unroll
    for (int p = 0; p < 38; p++) {
        float v = sh[PADI(qb + p)];
        #pragma unroll
        for (int sub = 0; sub < 4; sub++) {
            int idx = p + 3 - sub;
            a0c[sub] = __fmaf_rn(T0c[idx], v, a0c[sub]);
            a0s[sub] = __fmaf_rn(T0s[idx], v, a0s[sub]);
            a1c[sub] = __fmaf_rn(T1c[idx], v, a1c[sub]);
            a3c[sub] = __fmaf_rn(T3c[idx], v, a3c[sub]);
        }
    }
    size_t o = ((size_t)b*H + y)*W + qb;
    *(float4*)(h0c + o) = make_float4(a0c[0], a0c[1], a0c[2], a0c[3]);
    *(float4*)(h0s + o) = make_float4(a0s[0], a0s[1], a0s[2], a0s[3]);
    *(float4*)(h1c + o) = make_float4(a1c[0], a1c[1], a1c[2], a1c[3]);
    *(float4*)(h3c + o) = make_float4(a3c[0], a3c[1], a3c[2], a3c[3]);
}

// ------- Gabor V, 45/135 pair: A=Vc*hc, B=Vs*hs -> f0=A-B, f2=A+B -------
__global__ __launch_bounds__(128) void gaborVAB(
        const float* __restrict__ hc, const float* __restrict__ hs,
        float* __restrict__ f0, float* __restrict__ f2,
        const float* __restrict__ Tc, const float* __restrict__ Ts,
        float* __restrict__ p0, float* __restrict__ p2) {
    int bid = blockIdx.x;
    int b = bid & 7; int r_ = bid >> 3; int tile = r_ % 48; int strip = r_ / 48;
    int y0 = tile*TH, x = strip*128 + threadIdx.x;
    float A[TH], Bm[TH];
    #pragma unroll
    for (int k = 0; k < TH; k++) { A[k] = 0.f; Bm[k] = 0.f; }
    const size_t pb = (size_t)b*NP;
    for (int base = 0; base < 50; base += 2) {
        int gA = symref(y0 + base - 17, H), gB = symref(y0 + base - 16, H);
        size_t oA = pb + (size_t)gA*W + x, oB = pb + (size_t)gB*W + x;
        float vcA = hc[oA], vsA = hs[oA];
        float vcB = hc[oB], vsB = hs[oB];
        #pragma unroll
        for (int k = 0; k < TH; k++) {
            int i26 = base - k + 26;
            float t = A[k];
            t = __fmaf_rn(Tc[i26],   vcA, t);
            t = __fmaf_rn(Tc[i26+1], vcB, t);
            A[k] = t;
            t = Bm[k];
            t = __fmaf_rn(Ts[i26],   vsA, t);
            t = __fmaf_rn(Ts[i26+1], vsB, t);
            Bm[k] = t;
        }
    }
    int g64 = strip*2 + (threadIdx.x >> 6);
    bool l0 = (threadIdx.x & 63) == 0;
    #pragma unroll
    for (int k = 0; k < TH; k++) {
        size_t o = ((size_t)b*H + y0 + k)*W + x;
        size_t po = ((size_t)b*H + y0 + k)*12 + g64;
        float v0 = A[k] - Bm[k];
        float v2 = A[k] + Bm[k];
        f0[o] = v0;
        float s = v0;
        for (int off = 32; off; off >>= 1) s += __shfl_down(s, off);
        if (l0) p0[po] = s;
        f2[o] = v2;
        s = v2;
        for (int off = 32; off; off >>= 1) s += __shfl_down(s, off);
        if (l0) p2[po] = s;
    }
}

// ------- Gabor V, 90/180 pair: two independent 1-plane chains -------
__global__ __launch_bounds__(128) void gaborV13(
        const float* __restrict__ h1, const float* __restrict__ h3,
        float* __restrict__ f1, float* __restrict__ f3,
        const float* __restrict__ T1, const float* __restrict__ T3,
        float* __restrict__ p1, float* __restrict__ p3) {
    int bid = blockIdx.x;
    int b = bid & 7; int r_ = bid >> 3; int tile = r_ % 48; int strip = r_ / 48;
    int y0 = tile*TH, x = strip*128 + threadIdx.x;
    float a1[TH], a3[TH];
    #pragma unroll
    for (int k = 0; k < TH; k++) { a1[k] = 0.f; a3[k] = 0.f; }
    const size_t pb = (size_t)b*NP;
    for (int base = 0; base < 50; base += 2) {
        int gA = symref(y0 + base - 17, H), gB = symref(y0 + base - 16, H);
        size_t oA = pb + (size_t)gA*W + x, oB = pb + (size_t)gB*W + x;
        float v1A = h1[oA], v3A = h3[oA];
        float v1B = h1[oB], v3B = h3[oB];
        #pragma unroll
        for (int k = 0; k < TH; k++) {
            int i31 = base - k + 31;
            float t = a1[k];
            t = __fmaf_rn(T1[i31],   v1A, t);
            t = __fmaf_rn(T1[i31+1], v1B, t);
            a1[k] = t;
            t = a3[k];
            t = __fmaf_rn(T3[i31],   v3A, t);
            t = __fmaf_rn(T3[i31+1], v3B, t);
            a3[k] = t;
        }
    }
    int g64 = strip*2 + (threadIdx.x >> 6);
    bool l0 = (threadIdx.x & 63) == 0;
    #pragma unroll
    for (int k = 0; k < TH; k++) {
        size_t o = ((size_t)b*H + y0 + k)*W + x;
        size_t po = ((size_t)b*H + y0 + k)*12 + g64;
        f1[o] = a1[k];
        float s = a1[k];
        for (int off = 32; off; off >>= 1) s += __shfl_down(s, off);
        if (l0) p1[po] = s;
        f3[o] = a3[k];
        s = a3[k];
        for (int off = 32; off; off >>= 1) s += __shfl_down(s, off);
        if (l0) p3[po] = s;
    }
}

// ---------------- deterministic per-image sums, all 4 angles ----------------
__global__ void sumKAll(const float* __restrict__ p12, float* fsum) {
    int b = blockIdx.x, g = blockIdx.y, t = threadIdx.x;
    const float* P = p12 + (size_t)g*P12N;
    float s = 0.f;
    for (int k = 0; k < 9; k++) {
        int idx = t + k*256;                 // 0..2303 == row*3 + strip
        int row = idx / 3, strip = idx - row*3;
        const float* Q = P + ((size_t)b*H + row)*12 + strip*4;
        float p4 = ((Q[0] + Q[1]) + Q[2]) + Q[3];
        s += p4;
    }
    __shared__ float sm[256];
    sm[t] = s; __syncthreads();
    for (int off = 128; off; off >>= 1) {
        if (t < off) sm[t] += sm[t + off];
        __syncthreads();
    }
    if (t == 0) fsum[g*8 + b] = sm[0];
}

// ---------------- seeds: row-tiled, 4 planes sequential in LDS (XCD swizzle) ----------------
__global__ __launch_bounds__(256) void seedK4(const float* __restrict__ f0,
        const float* __restrict__ f1, const float* __restrict__ f2,
        const float* __restrict__ f3, const float* __restrict__ fsum,
        u64* __restrict__ seedB) {
    int bid = blockIdx.x;
    int b = bid & 7; int r_ = bid >> 3;          // 0..143
    int y0 = (r_ % 48)*16; int xb = r_ / 48;     // 0..2
    int x0 = xb*256, t = threadIdx.x;
    __shared__ float sh[18][258];
    const float* planes[4] = {f0, f1, f2, f3};
    unsigned condMask = 0;
    #pragma unroll
    for (int a = 0; a < 4; a++) {
        const float* F = planes[a] + (size_t)b*NP;
        __syncthreads();
        for (int idx = t; idx < 18*258; idx += 256) {
            int rr = idx / 258, q = idx - rr*258;
            int gy = y0 - 1 + rr; gy = gy < 0 ? 0 : (gy > H-1 ? H-1 : gy);
            int gx = x0 - 1 + q;  gx = gx < 0 ? 0 : (gx > W-1 ? W-1 : gx);
            sh[rr][q] = F[gy*W + gx];
        }
        __syncthreads();
        float mean = fsum[a*8 + b] / 589824.f;
        #pragma unroll
        for (int r = 0; r < 16; r++) {
            float c = sh[r+1][t+1];
            float mx = c;
            mx = fmaxf(mx, sh[r  ][t]); mx = fmaxf(mx, sh[r  ][t+1]); mx = fmaxf(mx, sh[r  ][t+2]);
            mx = fmaxf(mx, sh[r+1][t]); mx = fmaxf(mx, sh[r+1][t+1]); mx = fmaxf(mx, sh[r+1][t+2]);
            mx = fmaxf(mx, sh[r+2][t]); mx = fmaxf(mx, sh[r+2][t+1]); mx = fmaxf(mx, sh[r+2][t+2]);
            if ((c == mx) && (c > mean)) condMask |= (1u << r);
        }
    }
    int wv = t >> 6, lane = t & 63;
    #pragma unroll
    for (int r = 0; r < 16; r++) {
        u64 m = __ballot((condMask >> r) & 1u);
        if (lane == 0)
            seedB[((size_t)b*H + y0 + r)*WPR + xb*4 + wv] = m;
    }
}

// ---------------- Sobel grad mask (bitpacked, XCD swizzle) ----------------
__global__ void sobelK(const float* __restrict__ enh, u64* __restrict__ maskB) {
    int bid = blockIdx.x;
    int b = bid & 7; int r_ = bid >> 3;     // 0..2303
    int y = r_ / 3; int xs = r_ - 3*y;
    int x = xs*256 + threadIdx.x;
    const float* E = enh + (size_t)b*NP;
    int ym = y > 0 ? y-1 : 1, yp = y < H-1 ? y+1 : H-2;   // reflect101
    int xm = x > 0 ? x-1 : 1, xp = x < W-1 ? x+1 : W-2;
    float a00 = E[ym*W + xm], a01 = E[ym*W + x], a02 = E[ym*W + xp];
    float a10 = E[y*W + xm],                     a12 = E[y*W + xp];
    float a20 = E[yp*W + xm], a21 = E[yp*W + x], a22 = E[yp*W + xp];
    float gx = __fmaf_rn(-1.f, a00, 0.f);
    gx = __fmaf_rn( 1.f, a02, gx);
    gx = __fmaf_rn(-2.f, a10, gx);
    gx = __fmaf_rn( 2.f, a12, gx);
    gx = __fmaf_rn(-1.f, a20, gx);
    gx = __fmaf_rn( 1.f, a22, gx);
    float gy = __fmaf_rn(-1.f, a00, 0.f);
    gy = __fmaf_rn(-2.f, a01, gy);
    gy = __fmaf_rn(-1.f, a02, gy);
    gy = __fmaf_rn( 1.f, a20, gy);
    gy = __fmaf_rn( 2.f, a21, gy);
    gy = __fmaf_rn( 1.f, a22, gy);
    float s = __fadd_rn(__fmul_rn(gx, gx), __fmul_rn(gy, gy));
    float grad = (float)sqrt((double)s);
    const float THR = (float)(0.0789 + 1.0*0.0774);
    bool m = grad >= THR;
    u64 bits = __ballot(m);
    if ((threadIdx.x & 63) == 0) {
        int word = xs*4 + (threadIdx.x >> 6);
        maskB[((size_t)b*H + y)*WPR + word] = bits;
    }
}

// ------- flood: thread-per-row tiles (256 rows), O(1) horizontal run-fill, guarded passes -------
__global__ __launch_bounds__(256) void floodTileK(const u64* __restrict__ Mb,
        const u64* __restrict__ seedB, u64* __restrict__ Rb,
        unsigned* __restrict__ chg, int t) {
    if (t > 0 && chg[t-1] == 0) return;
    int b = blockIdx.y;
    int y0 = blockIdx.x * 256;
    int ty = threadIdx.x;
    int y = y0 + ty;
    const u64* M = Mb + (size_t)b*H*WPR;
    const u64* S = seedB + (size_t)b*H*WPR;
    u64* R = Rb + (size_t)b*H*WPR;
    u64 m[12], r[12], hT[12], hB[12];
    #pragma unroll
    for (int w = 0; w < 12; w++) {
        m[w] = M[y*WPR + w];
        r[w] = (t == 0) ? (m[w] & S[y*WPR + w]) : R[y*WPR + w];
    }
    bool topRow = (ty == 0), botRow = (ty == 255);
    // halo snapshot (only edge threads need it)
    #pragma unroll
    for (int w = 0; w < 12; w++) { hT[w] = 0ULL; hB[w] = 0ULL; }
    if (topRow && y0 > 0) {
        int hy = y0 - 1;
        #pragma unroll
        for (int w = 0; w < 12; w++)
            hT[w] = (t == 0) ? (M[hy*WPR+w] & S[hy*WPR+w]) : R[hy*WPR+w];
    }
    if (botRow && y0 + 256 < H) {
        int hy = y0 + 256;
        #pragma unroll
        for (int w = 0; w < 12; w++)
            hB[w] = (t == 0) ? (M[hy*WPR+w] & S[hy*WPR+w]) : R[hy*WPR+w];
    }
    __shared__ u64 L[256][12];
    __shared__ unsigned chgArr[4];
    #pragma unroll
    for (int w = 0; w < 12; w++) L[ty][w] = r[w];
    __syncthreads();
    int wvid = ty >> 6, lane = ty & 63;
    bool grew = false;
    while (true) {
        u64 D[12], F[12];
        #pragma unroll
        for (int w = 0; w < 12; w++) {
            u64 up = topRow ? hT[w] : L[ty-1][w];
            u64 dn = botRow ? hB[w] : L[ty+1][w];
            D[w] = r[w] | up | dn;
        }
        // seed: 1-step horizontal dilation (incl. cross-word) masked
        #pragma unroll
        for (int w = 0; w < 12; w++) {
            u64 s = D[w] | (D[w] << 1) | (D[w] >> 1);
            if (w > 0)  s |= D[w-1] >> 63;
            if (w < 11) s |= D[w+1] << 63;
            F[w] = s & m[w];
        }
        // upward (increasing col) run-fill with cross-word carry
        {
            u64 c = 0;
            #pragma unroll
            for (int w = 0; w < 12; w++) {
                u64 sd = (F[w] | c) & m[w];
                u64 uf = m[w] & ~(m[w] + sd);
                F[w] = uf | sd;
                c = uf >> 63;
            }
        }
        // downward run-fill via bit-reverse, cross-word carry
        {
            u64 c = 0;
            #pragma unroll
            for (int w = 11; w >= 0; w--) {
                u64 sd = (F[w] | (c << 63)) & m[w];
                u64 bm = __brevll(m[w]);
                u64 df = __brevll(bm & ~(bm + __brevll(sd)));
                F[w] = df | sd;
                c = df & 1ULL;
            }
        }
        bool chgT = false;
        #pragma unroll
        for (int w = 0; w < 12; w++) if (F[w] != r[w]) chgT = true;
        bool wc = __any(chgT);
        if (lane == 0) chgArr[wvid] = wc ? 1u : 0u;
        __syncthreads();                  // L reads done; chgArr visible
        #pragma unroll
        for (int w = 0; w < 12; w++) { r[w] = F[w]; L[ty][w] = F[w]; }
        unsigned any = chgArr[0] | chgArr[1] | chgArr[2] | chgArr[3];
        __syncthreads();                  // L writes visible; chgArr reads done
        if (!any) break;
        grew = true;
    }
    #pragma unroll
    for (int w = 0; w < 12; w++) R[y*WPR + w] = r[w];
    if (grew && ty == 0) atomicOr(&chg[t], 1u);
}

// ---------------- final: out = (sigmoid?(pred)>0.5) | reach ----------------
__global__ void finalK(const float* __restrict__ pred, const u64* __restrict__ reachB,
                       const unsigned* __restrict__ sc, float* __restrict__ out) {
    int b = blockIdx.z, y = blockIdx.y, x = blockIdx.x*256 + threadIdx.x;
    float pmn = fdec(sc[16 + b]), pmx = fdec(sc[24 + b]);
    bool needSig = (pmx > 1.0f) || (pmn < 0.0f);
    float p = pred[((size_t)b*H + y)*W + x];
    float pv;
    if (needSig) {
        float e = (float)exp(-(double)p);
        pv = 1.f / (1.f + e);
    } else {
        pv = p;
    }
    bool on = pv > 0.5f;
    u64 w = reachB[((size_t)b*H + y)*WPR + (x >> 6)];
    on = on || ((w >> (x & 63)) & 1ULL);
    out[((size_t)b*H + y)*W + x] = on ? 1.f : 0.f;
}

extern "C" void kernel_launch(void* const* d_in, const int* in_sizes, int n_in,
                              void* d_out, int out_size, void* d_ws, size_t ws_size,
                              hipStream_t stream) {
    const float* pred = (const float*)d_in[0];
    const float* img  = (const float*)d_in[1];
    float* out = (float*)d_out;
    char* ws = (char*)d_ws;

    float*    wtab   = (float*)(ws + 1024);
    unsigned* sc     = (unsigned*)(ws + 16384);
    float*    fsum   = ((float*)sc) + 32;
    unsigned* chg    = sc + 64;
    float*    p12    = (float*)(ws + 20480);
    u64*      maskB  = (u64*)(ws + 1310720);
    u64*      seedB  = (u64*)(ws + 1900544);
    u64*      reachB = (u64*)(ws + 2490368);
    const size_t PL = (size_t)NB*NP;                      // floats per plane
    float* plane = (float*)(ws + 4194304);
    float* b0  = plane;          // gauss tmp
    float* b1  = plane + PL;     // enh
    float* h0c = plane + 2*PL; float* h0s = plane + 3*PL;
    float* h1c = plane + 4*PL; float* h3c = plane + 5*PL;
    float* f0  = plane + 8*PL; float* f1 = plane + 9*PL;
    float* f2  = plane + 10*PL; float* f3 = plane + 11*PL;

    const float* gpadH = wtab;
    const float* gpadV = wtab + 128;

    initK<<<1, 256, 0, stream>>>(wtab, sc);
    reduceK<<<dim3(64, 8), 256, 0, stream>>>(img, pred, sc);

    dim3 gRow(768, 8);            // one image row per block
    gaussHK2<<<gRow, 192, 0, stream>>>(img, b0, gpadH, sc);
    gaussVK4<<<2304, 128, 0, stream>>>(b0, img, b1, gpadV, sc);

    sobelK<<<18432, 256, 0, stream>>>(b1, maskB);

    gaborHF4<<<gRow, 192, 0, stream>>>(b1, h0c, h0s, h1c, h3c, wtab);

    // 45/135 shared pair -> f0, f2
    gaborVAB<<<2304, 128, 0, stream>>>(h0c, h0s, f0, f2,
                                       wtab + 768, wtab + 896,
                                       p12, p12 + 2*P12N);
    // 90/180 pair -> f1, f3
    gaborV13<<<2304, 128, 0, stream>>>(h1c, h3c, f1, f3,
                                       wtab + 1024, wtab + 1408,
                                       p12 + P12N, p12 + 3*P12N);
    sumKAll<<<dim3(8, 4), 256, 0, stream>>>(p12, fsum);

    seedK4<<<1152, 256, 0, stream>>>(f0, f1, f2, f3, fsum, seedB);

    for (int t = 0; t < FLOOD_PASSES; t++)
        floodTileK<<<dim3(3, 8), 256, 0, stream>>>(maskB, seedB, reachB, chg, t);

    finalK<<<dim3(3, H, 8), 256, 0, stream>>>(pred, reachB, sc, out);
}